// Round 8
// baseline (53.523 us; speedup 1.0000x reference)
//
#include <hip/hip_runtime.h>

#define HH 160
#define WW 160
#define CC 32
#define NN 8
#define PIX (HH * WW)   // 25600

typedef float f32x2 __attribute__((ext_vector_type(2)));
typedef float f32x4 __attribute__((ext_vector_type(4)));

// Block: 640 threads = 8 channel-groups x 80 w-pairs (one FULL feature row).
// Each thread: 4 channels of a pixel PAIR. Keeps R6's full-row write
// coherence (block writes each plane's 2560 B row-pair contiguously) while
// halving store instructions (f32x4 = 1024 B per wave-store) and the
// per-pixel tap-load count (pair shares a 3x4 tap window). Kernel taps for
// the row staged in LDS, per-pair copies held as 36 f32x2 (72 VGPR).
__global__ __launch_bounds__(640, 4) void pixelconv_k(
    const float* __restrict__ feature,   // [8,32,160,160]
    const float* __restrict__ kern,      // [8,36,160,160]
    float* __restrict__ out)             // [8,32,320,320]
{
    const int bx = blockIdx.x;                 // 0..159
    const int h  = (bx & 7) * 20 + (bx >> 3);  // XCD-chunked h swizzle
    const int n  = blockIdx.y;                 // 0..7
    const int t  = threadIdx.x;                // 0..639
    const int p  = t % 80;                     // w-pair index (w0 = 2p)
    const int cg = t / 80;                     // 0..7 channel group (4 ch)
    const int w0 = 2 * p;

    // ---- stage kernel[n][0:36][h][0:160] into LDS ----
    __shared__ float kv_lds[36 * 160];
    const float* kbase = kern + (size_t)n * 36 * PIX + (size_t)h * WW;
    #pragma unroll
    for (int r = 0; r < 9; ++r) {
        const int idx = t + r * 640;           // 5760 = 9 * 640 exactly
        const int j   = idx / 160;
        const int ws  = idx - j * 160;
        kv_lds[idx] = kbase[(size_t)j * PIX + ws];
    }
    __syncthreads();

    // per-thread taps for BOTH pixels of the pair (ds_read_b64, 2-way = free)
    f32x2 kv[36];
    #pragma unroll
    for (int j = 0; j < 36; ++j) kv[j] = *(const f32x2*)&kv_lds[j * 160 + w0];

    const bool hm = (h > 0), hp = (h < HH - 1);
    const bool wm = (p > 0), wp = (p < 79);

    const float* fc = feature + ((size_t)(n * CC + cg * 4)) * PIX
                              + (size_t)h * WW + w0;
    float* oc = out + ((size_t)(n * CC + cg * 4)) * 4 * PIX
                    + (size_t)(2 * h) * (2 * WW) + 2 * w0;

    #pragma unroll
    for (int i = 0; i < 4; ++i) {
        // rows h-1..h+1, cols w0-1..w0+2 -> r[3][4]
        float r[3][4];
        #pragma unroll
        for (int dy = 0; dy < 3; ++dy) {
            const bool okh = (dy == 1) || (dy == 0 ? hm : hp);
            const float* rowp = fc + (dy - 1) * WW;
            f32x2 mid = okh ? *(const f32x2*)rowp : (f32x2){0.f, 0.f};
            r[dy][1] = mid.x;
            r[dy][2] = mid.y;
            r[dy][0] = (okh && wm) ? rowp[-1] : 0.f;
            r[dy][3] = (okh && wp) ? rowp[2]  : 0.f;
        }

        float a00 = 0.f, a01 = 0.f, a02 = 0.f, a03 = 0.f;   // pixel w0
        float a10 = 0.f, a11 = 0.f, a12 = 0.f, a13 = 0.f;   // pixel w0+1
        #pragma unroll
        for (int dx = 0; dx < 3; ++dx) {
            #pragma unroll
            for (int dy = 0; dy < 3; ++dy) {
                const int k = dx * 3 + dy;
                const float f0 = r[dy][dx];      // col w0 + dx - 1
                const float f1 = r[dy][dx + 1];  // col w0 + dx
                a00 = fmaf(f0, kv[4 * k + 0].x, a00);
                a01 = fmaf(f0, kv[4 * k + 1].x, a01);
                a02 = fmaf(f0, kv[4 * k + 2].x, a02);
                a03 = fmaf(f0, kv[4 * k + 3].x, a03);
                a10 = fmaf(f1, kv[4 * k + 0].y, a10);
                a11 = fmaf(f1, kv[4 * k + 1].y, a11);
                a12 = fmaf(f1, kv[4 * k + 2].y, a12);
                a13 = fmaf(f1, kv[4 * k + 3].y, a13);
            }
        }

        // pixel shuffle: row 2h cols 4p..4p+3, row 2h+1 cols 4p..4p+3
        *(f32x4*)(oc)          = (f32x4){a00, a01, a10, a11};
        *(f32x4*)(oc + 2 * WW) = (f32x4){a02, a03, a12, a13};

        fc += PIX;               // next channel's feature plane
        oc += (size_t)4 * PIX;   // next channel's output plane
    }
}

extern "C" void kernel_launch(void* const* d_in, const int* in_sizes, int n_in,
                              void* d_out, int out_size, void* d_ws, size_t ws_size,
                              hipStream_t stream) {
    const float* feature = (const float*)d_in[0];
    const float* kern    = (const float*)d_in[1];
    float* out           = (float*)d_out;

    dim3 grid(HH, NN, 1);   // (160, 8)
    pixelconv_k<<<grid, 640, 0, stream>>>(feature, kern, out);
}

// Round 9
// 45.500 us; speedup vs baseline: 1.1763x; 1.1763x over previous
//
#include <hip/hip_runtime.h>

#define HH 160
#define WW 160
#define CC 32
#define NN 8
#define PIX (HH * WW)   // 25600

typedef float f32x2 __attribute__((ext_vector_type(2)));
typedef float f32x4 __attribute__((ext_vector_type(4)));

// Block: 640 threads = 4 cg x 2 subpixel-halves x 80 w-pairs (full row).
// Each thread: 8 channels, one pixel PAIR, one output row (2h+half).
// Produces 4 consecutive output floats per channel -> one f32x4 NT store.
// kv register footprint: 18 f32x2 = 36 VGPRs (half the subpixels), so no
// spill (R7's failure). Keeps R6's full-row write coherence; NT stores keep
// the 105 MB write stream out of L3 so inputs stay L3-resident.
__global__ __launch_bounds__(640, 5) void pixelconv_k(
    const float* __restrict__ feature,   // [8,32,160,160]
    const float* __restrict__ kern,      // [8,36,160,160]
    float* __restrict__ out)             // [8,32,320,320]
{
    const int bx = blockIdx.x;                 // 0..159
    const int h  = (bx & 7) * 20 + (bx >> 3);  // XCD-chunked h swizzle
    const int n  = blockIdx.y;                 // 0..7
    const int t  = threadIdx.x;                // 0..639
    const int p    = t % 80;                   // w-pair (w0 = 2p)
    const int half = (t / 80) & 1;             // 0: row 2h, 1: row 2h+1
    const int cg   = t / 160;                  // 0..3 (8 channels each)
    const int w0 = 2 * p;

    // ---- stage kernel[n][0:36][h][0:160] into LDS ----
    __shared__ float kv_lds[36 * 160];
    const float* kbase = kern + (size_t)n * 36 * PIX + (size_t)h * WW;
    #pragma unroll
    for (int r = 0; r < 9; ++r) {
        const int idx = t + r * 640;           // 5760 = 9 * 640 exactly
        const int j   = idx / 160;
        const int ws  = idx - j * 160;
        kv_lds[idx] = kbase[(size_t)j * PIX + ws];
    }
    __syncthreads();

    // taps for this thread's 2 subpixels (j = 4k + 2*half + r2), both pixels
    // kvA[k] = (px0, px1) for r2=0 ; kvB[k] = (px0, px1) for r2=1
    f32x2 kvA[9], kvB[9];
    #pragma unroll
    for (int k = 0; k < 9; ++k) {
        kvA[k] = *(const f32x2*)&kv_lds[(4 * k + 2 * half)     * 160 + w0];
        kvB[k] = *(const f32x2*)&kv_lds[(4 * k + 2 * half + 1) * 160 + w0];
    }

    const bool hm = (h > 0), hp = (h < HH - 1);
    const bool wm = (p > 0), wp = (p < 79);

    const float* fc = feature + ((size_t)(n * CC + cg * 8)) * PIX
                              + (size_t)h * WW + w0;
    float* oc = out + ((size_t)(n * CC + cg * 8)) * 4 * PIX
                    + (size_t)(2 * h + half) * (2 * WW) + 4 * p;

    #pragma unroll 2
    for (int i = 0; i < 8; ++i) {
        // rows h-1..h+1, cols w0-1..w0+2 -> r[3][4]
        float r[3][4];
        #pragma unroll
        for (int dy = 0; dy < 3; ++dy) {
            const bool okh = (dy == 1) || (dy == 0 ? hm : hp);
            const float* rowp = fc + (dy - 1) * WW;
            f32x2 mid = okh ? *(const f32x2*)rowp : (f32x2){0.f, 0.f};
            r[dy][1] = mid.x;
            r[dy][2] = mid.y;
            r[dy][0] = (okh && wm) ? rowp[-1] : 0.f;
            r[dy][3] = (okh && wp) ? rowp[2]  : 0.f;
        }

        // 4 outputs: (px0,r2=0), (px0,r2=1), (px1,r2=0), (px1,r2=1)
        float a00 = 0.f, a01 = 0.f, a10 = 0.f, a11 = 0.f;
        #pragma unroll
        for (int dx = 0; dx < 3; ++dx) {
            #pragma unroll
            for (int dy = 0; dy < 3; ++dy) {
                const int k = dx * 3 + dy;
                const float f0 = r[dy][dx];      // px0 tap
                const float f1 = r[dy][dx + 1];  // px1 tap
                a00 = fmaf(f0, kvA[k].x, a00);
                a01 = fmaf(f0, kvB[k].x, a01);
                a10 = fmaf(f1, kvA[k].y, a10);
                a11 = fmaf(f1, kvB[k].y, a11);
            }
        }

        // one contiguous f32x4 of output row (2h+half), cols 4p..4p+3
        __builtin_nontemporal_store((f32x4){a00, a01, a10, a11}, (f32x4*)oc);

        fc += PIX;               // next channel's feature plane
        oc += (size_t)4 * PIX;   // next channel's output plane
    }
}

extern "C" void kernel_launch(void* const* d_in, const int* in_sizes, int n_in,
                              void* d_out, int out_size, void* d_ws, size_t ws_size,
                              hipStream_t stream) {
    const float* feature = (const float*)d_in[0];
    const float* kern    = (const float*)d_in[1];
    float* out           = (float*)d_out;

    dim3 grid(HH, NN, 1);   // (160, 8)
    pixelconv_k<<<grid, 640, 0, stream>>>(feature, kern, out);
}